// Round 1
// baseline (65.600 us; speedup 1.0000x reference)
//
#include <hip/hip_runtime.h>

// CrossModalCenterLoss collapses analytically:
//   dist = distmat * one_hot(labels)  -> only distmat[b, labels[b]] survives;
//   clip(0, 1e-12, 1e12) = 1e-12 for the B*(C-1) masked entries.
//   loss = mean_b clip(||x_b - centers[l_b]||^2) + (C-1)*1e-12
// So: gather 4096 center rows, squared distance, reduce. ~8 MB traffic total.

#define BATCH      4096
#define FEAT_DIM   256
#define NUM_CLS    10000
#define CLAMP_MIN_F 1e-12f
#define CLAMP_MAX_F 1e12f

// One wave (64 lanes) per row; 4 rows per 256-thread block; 1024 blocks.
__global__ __launch_bounds__(256) void cmcl_row_dist(
    const float* __restrict__ x,
    const int*   __restrict__ labels,
    const float* __restrict__ centers,
    float*       __restrict__ partial)   // [1024] per-block partial sums
{
    const int lane = threadIdx.x & 63;
    const int wave = threadIdx.x >> 6;
    const int row  = (blockIdx.x << 2) + wave;   // < 4096 exactly

    const int label = labels[row];
    const float4* __restrict__ xr = (const float4*)(x       + (size_t)row   * FEAT_DIM);
    const float4* __restrict__ cr = (const float4*)(centers + (size_t)label * FEAT_DIM);

    // 64 lanes * 4 floats = 256 = FEAT_DIM, one float4 per lane.
    float4 xv = xr[lane];
    float4 cv = cr[lane];
    float dx = xv.x - cv.x;
    float dy = xv.y - cv.y;
    float dz = xv.z - cv.z;
    float dw = xv.w - cv.w;
    float v = dx*dx + dy*dy + dz*dz + dw*dw;

    // wave-64 shuffle reduction
    #pragma unroll
    for (int off = 32; off > 0; off >>= 1)
        v += __shfl_down(v, off, 64);

    __shared__ float sm[4];
    if (lane == 0) {
        // clamp applied per masked element (the surviving diagonal entry)
        v = fminf(fmaxf(v, CLAMP_MIN_F), CLAMP_MAX_F);
        sm[wave] = v;
    }
    __syncthreads();
    if (threadIdx.x == 0)
        partial[blockIdx.x] = sm[0] + sm[1] + sm[2] + sm[3];
}

// Single-block deterministic reduction of the 1024 partials.
__global__ __launch_bounds__(256) void cmcl_reduce(
    const float* __restrict__ partial,
    float*       __restrict__ out)
{
    float v = partial[threadIdx.x]
            + partial[threadIdx.x + 256]
            + partial[threadIdx.x + 512]
            + partial[threadIdx.x + 768];

    #pragma unroll
    for (int off = 32; off > 0; off >>= 1)
        v += __shfl_down(v, off, 64);

    __shared__ float sm[4];
    const int lane = threadIdx.x & 63;
    const int wave = threadIdx.x >> 6;
    if (lane == 0) sm[wave] = v;
    __syncthreads();
    if (threadIdx.x == 0) {
        float total = sm[0] + sm[1] + sm[2] + sm[3];
        // + clamp-floor contribution of the (C-1) masked zeros per row:
        // B*(C-1)*1e-12 / B = (C-1)*1e-12
        out[0] = total / (float)BATCH + (float)(NUM_CLS - 1) * CLAMP_MIN_F;
    }
}

extern "C" void kernel_launch(void* const* d_in, const int* in_sizes, int n_in,
                              void* d_out, int out_size, void* d_ws, size_t ws_size,
                              hipStream_t stream) {
    const float* x       = (const float*)d_in[0];
    const int*   labels  = (const int*)  d_in[1];
    const float* centers = (const float*)d_in[2];
    float*       out     = (float*)d_out;
    float*       partial = (float*)d_ws;   // 1024 floats = 4 KB

    cmcl_row_dist<<<BATCH / 4, 256, 0, stream>>>(x, labels, centers, partial);
    cmcl_reduce<<<1, 256, 0, stream>>>(partial, out);
}